// Round 3
// baseline (422.463 us; speedup 1.0000x reference)
//
#include <hip/hip_runtime.h>

#define NN 20000
#define EE 320000
#define BB 64
#define DD 256
#define DEPTH 3
#define NT (NN + BB)   // h rows + hs rows appended (NT = 20064 = 16*1254 = 32*627 = 8*2508)

typedef __attribute__((ext_vector_type(8))) short short8;
typedef __attribute__((ext_vector_type(4))) float floatx4;

// ---------------------------------------------------------------- bf16 split helpers
__device__ __forceinline__ short f2bf(float x) {
  union { float f; unsigned u; } v; v.f = x;
  unsigned r = v.u + 0x7fffu + ((v.u >> 16) & 1u);  // RNE
  return (short)(r >> 16);
}
__device__ __forceinline__ float bf2f(short s) {
  union { unsigned u; float f; } v; v.u = ((unsigned)(unsigned short)s) << 16;
  return v.f;
}

// round-20: L1-bypass loads for zero-reuse streams. kAgg's random hg gathers and
// kUpdM's wave-private B fragments have no L1 reuse; every access burns an L1-MSHR
// round trip (measured wall: both kernels pinned at ~43us = per-CU line-service
// limit, MfmaUtil~0, VALUBusy<70, hbm<12%). Nontemporal loads skip L1 allocation.
__device__ __forceinline__ short8 ntl8(const short* p) {
  return __builtin_nontemporal_load((const short8*)p);
}

// ---------------------------------------------------------------- fragment-order split store
// A-fragment layout: Af[(((row>>4)*8 + kc)*2 + plane)*512 + (kg*16 + (row&15))*8 + kel]
// (shorts; plane 0 = hi, 1 = lo; kc = k>>5, kg = (k>>3)&3, kel = k&7). A wave's 16x32
// fragment is ONE contiguous coalesced 1KB load in kUpdM.
// storeFragRow8: 8 consecutive cols (c0 % 8 == 0) of one row -> two 16B stores.
__device__ __forceinline__ void storeFragRow8(short* __restrict__ P, int row, int c0,
                                              const float* a) {
  short8 H, L;
  #pragma unroll
  for (int k = 0; k < 8; k++) {
    short hh = f2bf(a[k]);
    H[k] = hh;
    L[k] = f2bf(a[k] - bf2f(hh));
  }
  int kc = c0 >> 5, kg = (c0 >> 3) & 3;
  size_t u = ((size_t)((row >> 4) * 8 + kc) * 2) * 512 + (size_t)(kg * 16 + (row & 15)) * 8;
  *(short8*)(P + u) = H;
  *(short8*)(P + u + 512) = L;
}

// ---------------------------------------------------------------- reductions
__device__ __forceinline__ float blockSum256(float v, float* tmp) {
  #pragma unroll
  for (int o = 32; o > 0; o >>= 1) v += __shfl_down(v, o, 64);
  if ((threadIdx.x & 63) == 0) tmp[threadIdx.x >> 6] = v;
  __syncthreads();
  float r = tmp[0] + tmp[1] + tmp[2] + tmp[3];
  __syncthreads();
  return r;
}

// ---------------------------------------------------------------- kPre: rank atomics + kM + encode
// SINGLE atomic pass over edges (round-13). B in MFMA-fragment order (round-15/16).
// Encode 16-rows-per-block with LDS transpose -> coalesced Af writes (round-19).
#define NCB ((EE + 255) / 256)   // 1250
__global__ __launch_bounds__(256) void kPre(const float* __restrict__ X,
                                            const float* __restrict__ Xs,
                                            const float* __restrict__ W1,
                                            short* __restrict__ hg,
                                            short* __restrict__ Af,
                                            const int* __restrict__ dst,
                                            const int* __restrict__ bassign,
                                            int* curn, int* curb,
                                            int* __restrict__ rank,
                                            int* __restrict__ rankB,
                                            const float* __restrict__ W2,
                                            const float* __restrict__ W3,
                                            const float* __restrict__ linW,
                                            short* __restrict__ Bf) {
  __shared__ int hb[64], rs[64], hc[64];
  __shared__ __align__(16) short Hs[16][264];   // 264: stride 132 dwords %32 = 4 -> <=2-way
  __shared__ __align__(16) short Ls[16][264];
  int bid = blockIdx.x, j = threadIdx.x;
  if (bid < NCB) {
    if (j < 64) { hb[j] = 0; hc[j] = 0; }
    __syncthreads();
    int t = bid * 256 + j;
    int b = -1;
    if (t < NN) { b = bassign[t]; atomicAdd(&hb[b], 1); }
    __syncthreads();
    if (j < 64 && hb[j] > 0) rs[j] = atomicAdd(&curb[j], hb[j]);
    __syncthreads();
    if (t < NN) rankB[t] = rs[b] + atomicAdd(&hc[b], 1);
    if (t < EE) rank[t] = atomicAdd(&curn[dst[t]], 1);
  } else if (bid < NCB + 512) {
    // ---- M2 = W2 @ linW[0:256,:], M3 = W3 @ linW[256:512,:], fragment-order split
    int i = (bid - NCB) & 255;
    bool second = (bid - NCB) >= 256;
    const float* W = second ? W3 : W2;
    const float* L = linW + (second ? DD * DD : 0);
    float acc = 0.f;
    #pragma unroll 4
    for (int k = 0; k < DD; k++) acc = fmaf(W[i * DD + k], L[k * DD + j], acc);
    short hi = f2bf(acc);
    short lo = f2bf(acc - bf2f(hi));
    int kk = second ? (DD + i) : i;          // k index in B' (0..511)
    int kc = kk >> 5, kg = (kk >> 3) & 3, kel = kk & 7;
    int n16 = j >> 4, m16 = j & 15;
    size_t idx = ((size_t)(kc * 16 + n16) * 2) * 512 + (kg * 16 + m16) * 8 + kel;
    Bf[idx] = hi;
    Bf[idx + 512] = lo;
  } else {
    // ---- encode: 16 rows per block, 16 threads/row x 16 cols/thread
    int rg = bid - NCB - 512;        // row-group 0..1253
    int rl = j >> 4;                 // row-in-group 0..15 (16 lanes each, shfl<16 safe)
    int ci = j & 15;
    int r = rg * 16 + rl;
    int c0 = ci * 16;
    const float* x = (r < NN) ? (X + (size_t)r * 2) : (Xs + (size_t)(r - NN) * 2);
    float x0 = x[0], x1 = x[1];
    float v[16];
    float ss = 0.f;
    #pragma unroll
    for (int q = 0; q < 4; q++) {
      float4 wa = *(const float4*)(W1 + c0 + q * 4);
      float4 wb = *(const float4*)(W1 + DD + c0 + q * 4);
      float a0 = fmaxf(fmaf(x0, wa.x, x1 * wb.x), 0.f);
      float a1 = fmaxf(fmaf(x0, wa.y, x1 * wb.y), 0.f);
      float a2 = fmaxf(fmaf(x0, wa.z, x1 * wb.z), 0.f);
      float a3 = fmaxf(fmaf(x0, wa.w, x1 * wb.w), 0.f);
      v[q * 4 + 0] = a0; v[q * 4 + 1] = a1; v[q * 4 + 2] = a2; v[q * 4 + 3] = a3;
      ss = fmaf(a0, a0, ss); ss = fmaf(a1, a1, ss);
      ss = fmaf(a2, a2, ss); ss = fmaf(a3, a3, ss);
    }
    #pragma unroll
    for (int o = 1; o < 16; o <<= 1) ss += __shfl_xor(ss, o, 64);
    float inv = 1.f / fmaxf(sqrtf(ss), 1e-12f);
    short8 H0, H1, L0, L1;
    #pragma unroll
    for (int k = 0; k < 8; k++) {
      float s0 = v[k] * inv;
      float s1 = v[8 + k] * inv;
      short h0 = f2bf(s0), h1 = f2bf(s1);
      H0[k] = h0; H1[k] = h1;
      L0[k] = f2bf(s0 - bf2f(h0)); L1[k] = f2bf(s1 - bf2f(h1));
    }
    *(short8*)(hg + (size_t)r * DD + c0)     = H0;
    *(short8*)(hg + (size_t)r * DD + c0 + 8) = H1;
    *(short8*)&Hs[rl][c0] = H0;  *(short8*)&Hs[rl][c0 + 8] = H1;
    *(short8*)&Ls[rl][c0] = L0;  *(short8*)&Ls[rl][c0 + 8] = L1;
    __syncthreads();
    // ---- coalesced fragment write: thread j covers fragment kc=j>>5, positions j&31, +32
    int kc = j >> 5, p0 = j & 31;
    #pragma unroll
    for (int half = 0; half < 2; half++) {
      int p = p0 + half * 32;
      int prow = p & 15, kg = p >> 4;
      size_t ub = ((size_t)(rg * 8 + kc) * 2) * 512 + (size_t)p * 8;
      *(short8*)(Af + ub)       = *(const short8*)&Hs[prow][kc * 32 + kg * 8];
      *(short8*)(Af + ub + 512) = *(const short8*)&Ls[prow][kc * 32 + kg * 8];
    }
  }
}

// ---------------------------------------------------------------- CSR scan (counts live in curn/curb)
__global__ __launch_bounds__(1024) void kScan(const int* __restrict__ curn,
                                              int* offn,
                                              const int* __restrict__ curb,
                                              int* offb) {
  __shared__ int sums[1024];
  int t = threadIdx.x;
  const int CH = 20;  // 1024*20 = 20480 >= NN
  int base = t * CH;
  int local[CH];
  int s = 0;
  #pragma unroll
  for (int i = 0; i < CH; i++) {
    int idx = base + i;
    int v = (idx < NN) ? curn[idx] : 0;
    local[i] = s;
    s += v;
  }
  sums[t] = s;
  __syncthreads();
  for (int o = 1; o < 1024; o <<= 1) {
    int x = (t >= o) ? sums[t - o] : 0;
    __syncthreads();
    sums[t] += x;
    __syncthreads();
  }
  int excl = sums[t] - s;
  #pragma unroll
  for (int i = 0; i < CH; i++) {
    int idx = base + i;
    if (idx < NN) offn[idx] = excl + local[i];
  }
  if (t == 1023) offn[NN] = sums[1023];
  // batch offsets: 64-lane shuffle scan (first wave)
  if (t < 64) {
    int v = curb[t];
    int incl = v;
    #pragma unroll
    for (int o = 1; o < 64; o <<= 1) {
      int x = __shfl_up(incl, o, 64);
      if (t >= o) incl += x;
    }
    offb[t] = incl - v;
    if (t == 63) offb[BB] = incl;
  }
}

// ---------------------------------------------------------------- kPlace: rank -> position, no atomics
__global__ __launch_bounds__(256) void kPlace(const int* __restrict__ src,
                                              const int* __restrict__ dst,
                                              const float* __restrict__ w,
                                              const int* __restrict__ bassign,
                                              const int* __restrict__ offn,
                                              const int* __restrict__ offb,
                                              const int* __restrict__ rank,
                                              const int* __restrict__ rankB,
                                              long long* sedge, int* snode) {
  int t = blockIdx.x * 256 + threadIdx.x;
  if (t < EE) {
    unsigned long long e = (unsigned long long)(unsigned)src[t]
                         | ((unsigned long long)(unsigned)__float_as_int(w[t]) << 32);
    sedge[offn[dst[t]] + rank[t]] = (long long)e;
  }
  if (t < NN) snode[offb[bassign[t]] + rankB[t]] = t;
}

// ---------------------------------------------------------------- aggregation (XCD-sliced, 8 waves = 8 nodes)
// round-19: bf16 hg gathers (4 slices x 64 cols, one 128B line per edge-slice);
// slice = bid&3 pins each XCD to one slice -> 2.56MB/XCD, L2-resident.
// round-20: hg gathers + sedge/snode staging loads are NONTEMPORAL (zero L1 reuse;
// the ~43us wall is per-CU L1-miss line service, not BW -- MfmaUtil 0, hbm ~10%).
#define ECAP 1024   // staged edges per chunk (8 KB)
__global__ __launch_bounds__(512) void kAgg(const short* __restrict__ hg,
                                            const int* __restrict__ offn,
                                            const long long* __restrict__ sedge,
                                            const int* __restrict__ offb,
                                            const int* __restrict__ snode,
                                            short* __restrict__ Avf) {
  __shared__ __align__(16) long long Led[ECAP];
  int bid = blockIdx.x;
  int slice = bid & 3, group = bid >> 2;      // group 0..2507
  int t = threadIdx.x;
  int w = t >> 6, lane = t & 63;
  int eg = lane >> 3;          // edge group 0..7
  int pc = lane & 7;           // 16B piece 0..7
  int colB = slice * 64 + pc * 8;             // 8 bf16 cols per lane
  float acc[8];
  #pragma unroll
  for (int jj = 0; jj < 8; jj++) acc[jj] = 0.f;

  if (group < 8) {
    // ---- batch rows: nodes 0..63 (8 per block), snode index list (weight 1)
    int b0 = group * 8;
    int s0 = offb[b0], e0 = offb[b0 + 8];
    int sW = offb[b0 + w], eW = offb[b0 + w + 1];
    int* Li = (int*)Led;
    for (int base = s0; base < e0; base += 2 * ECAP) {
      int cnt = min(e0 - base, 2 * ECAP);
      __syncthreads();
      for (int i = t; i < cnt; i += 512) Li[i] = __builtin_nontemporal_load(&snode[base + i]);
      __syncthreads();
      int lo = max(sW, base), hi = min(eW, base + cnt);
      for (int i = lo; i < hi; i += 16) {
        int i0 = i + eg, i1 = i + 8 + eg;
        int n0 = Li[min(i0, hi - 1) - base];
        int n1 = Li[min(i1, hi - 1) - base];
        float w0 = (i0 < hi) ? 1.f : 0.f;
        float w1 = (i1 < hi) ? 1.f : 0.f;
        short8 a0 = ntl8(hg + (size_t)n0 * DD + colB);
        short8 a1 = ntl8(hg + (size_t)n1 * DD + colB);
        #pragma unroll
        for (int jj = 0; jj < 8; jj++)
          acc[jj] = fmaf(w1, bf2f(a1[jj]), fmaf(w0, bf2f(a0[jj]), acc[jj]));
      }
    }
    #pragma unroll
    for (int o = 8; o < 64; o <<= 1)
      #pragma unroll
      for (int jj = 0; jj < 8; jj++) acc[jj] += __shfl_xor(acc[jj], o, 64);
    if (eg == 0) storeFragRow8(Avf, NN + b0 + w, colB, acc);
  } else {
    // ---- edge nodes, 8 per block
    int first = (group - 8) * 8;
    int s0 = offn[first], e0 = offn[first + 8];
    int sW = offn[first + w], eW = offn[first + w + 1];
    for (int base = s0; base < e0; base += ECAP) {
      int cnt = min(e0 - base, ECAP);
      __syncthreads();
      for (int i = t; i < cnt; i += 512) Led[i] = __builtin_nontemporal_load(&sedge[base + i]);
      __syncthreads();
      int lo = max(sW, base), hi = min(eW, base + cnt);
      for (int i = lo; i < hi; i += 16) {
        int i0 = i + eg, i1 = i + 8 + eg;
        long long e0v = Led[min(i0, hi - 1) - base];
        long long e1v = Led[min(i1, hi - 1) - base];
        float w0 = (i0 < hi) ? __int_as_float((int)(e0v >> 32)) : 0.f;
        float w1 = (i1 < hi) ? __int_as_float((int)(e1v >> 32)) : 0.f;
        unsigned r0 = (unsigned)(e0v & 0xffffffffLL);
        unsigned r1 = (unsigned)(e1v & 0xffffffffLL);
        short8 a0 = ntl8(hg + (size_t)r0 * DD + colB);
        short8 a1 = ntl8(hg + (size_t)r1 * DD + colB);
        #pragma unroll
        for (int jj = 0; jj < 8; jj++)
          acc[jj] = fmaf(w1, bf2f(a1[jj]), fmaf(w0, bf2f(a0[jj]), acc[jj]));
      }
    }
    #pragma unroll
    for (int o = 8; o < 64; o <<= 1)
      #pragma unroll
      for (int jj = 0; jj < 8; jj++) acc[jj] += __shfl_xor(acc[jj], o, 64);
    if (eg == 0) storeFragRow8(Avf, first + w, colB, acc);
  }
}

// ---------------------------------------------------------------- MFMA dual-GEMM + fused l2norm
// Barrier-free main loop: A pre-split in fragment order (L1-shared across the 8
// waves -> keep cached); B fragments are WAVE-PRIVATE (each wave distinct cols,
// 512KB/block streams through 32KB L1 with zero reuse) -> round-20: nontemporal
// B loads to skip L1 allocation. Af updated IN PLACE. Epilogue bounces the
// normalized f32 tile through LDS Ct -> coalesced Af + bf16 hg stores.
#define TRU 32
__global__ __launch_bounds__(512) void kUpdM(short* __restrict__ Af,
                                             const short* __restrict__ Avf,
                                             const short* __restrict__ Bf,
                                             const float* __restrict__ lb,
                                             short* __restrict__ hg) {
  __shared__ float ssq[8][TRU];
  __shared__ __align__(16) float Ct[TRU][260];
  const int t = threadIdx.x;
  const int rb = blockIdx.x * TRU;
  const int wid = t >> 6;          // 0..7
  const int lane = t & 63;
  const int wc = wid * 32;         // wave col offset (8 waves cover 256 cols)
  const int m16 = lane & 15;
  const int kg = lane >> 4;        // 0..3
  const int r16b = rb >> 4;

  floatx4 acc[2][2];
  #pragma unroll
  for (int ct = 0; ct < 2; ct++) {
    float b = lb[wc + ct * 16 + m16];
    #pragma unroll
    for (int rt = 0; rt < 2; rt++) acc[rt][ct] = (floatx4){b, b, b, b};
  }

  for (int half = 0; half < 2; ++half) {
    const short* Ab = half ? Avf : (const short*)Af;
    #pragma unroll 2
    for (int kcl = 0; kcl < 8; ++kcl) {
      const int kc = half * 8 + kcl;
      short8 ah[2], al_[2];
      #pragma unroll
      for (int rt = 0; rt < 2; rt++) {
        const short* ap = Ab + ((size_t)((r16b + rt) * 8 + kcl) * 2) * 512 + lane * 8;
        ah[rt]  = *(const short8*)ap;
        al_[rt] = *(const short8*)(ap + 512);
      }
      #pragma unroll
      for (int ct = 0; ct < 2; ct++) {
        const short* bp = Bf + ((size_t)(kc * 16 + wid * 2 + ct) * 2) * 512 + lane * 8;
        short8 bh = ntl8(bp);
        short8 bl = ntl8(bp + 512);
        #pragma unroll
        for (int rt = 0; rt < 2; rt++) {
          acc[rt][ct] = __builtin_amdgcn_mfma_f32_16x16x32_bf16(ah[rt], bh, acc[rt][ct], 0, 0, 0);
          acc[rt][ct] = __builtin_amdgcn_mfma_f32_16x16x32_bf16(ah[rt], bl, acc[rt][ct], 0, 0, 0);
          acc[rt][ct] = __builtin_amdgcn_mfma_f32_16x16x32_bf16(al_[rt], bh, acc[rt][ct], 0, 0, 0);
        }
      }
    }
  }

  // ---- epilogue: relu + row l2norm (C/D: col=lane&15, row=(lane>>4)*4+reg)
  float p[2][4];
  #pragma unroll
  for (int rt = 0; rt < 2; rt++)
    #pragma unroll
    for (int reg = 0; reg < 4; reg++) {
      float s = 0.f;
      #pragma unroll
      for (int ct = 0; ct < 2; ct++) {
        float x = fmaxf(acc[rt][ct][reg], 0.f);
        s = fmaf(x, x, s);
      }
      p[rt][reg] = s;
    }
  #pragma unroll
  for (int o = 1; o < 16; o <<= 1)
    #pragma unroll
    for (int rt = 0; rt < 2; rt++)
      #pragma unroll
      for (int reg = 0; reg < 4; reg++)
        p[rt][reg] += __shfl_xor(p[rt][reg], o, 64);
  if (m16 == 0) {
    #pragma unroll
    for (int rt = 0; rt < 2; rt++)
      #pragma unroll
      for (int reg = 0; reg < 4; reg++)
        ssq[wid][rt * 16 + kg * 4 + reg] = p[rt][reg];
  }
  __syncthreads();
  #pragma unroll
  for (int rt = 0; rt < 2; rt++) {
    #pragma unroll
    for (int reg = 0; reg < 4; reg++) {
      int row = rt * 16 + kg * 4 + reg;
      float ss = 0.f;
      #pragma unroll
      for (int ww = 0; ww < 8; ww++) ss += ssq[ww][row];
      float inv = 1.f / fmaxf(sqrtf(ss), 1e-12f);
      #pragma unroll
      for (int ct = 0; ct < 2; ct++) {
        int col = wc + ct * 16 + m16;
        Ct[row][col] = fmaxf(acc[rt][ct][reg], 0.f) * inv;
      }
    }
  }
  __syncthreads();
  // ---- fragment-order split write-back (in-place Af) + bf16 hg, 16B stores
  const int fl = lane;                 // lane-in-fragment
  const int fk = wid;                  // kc 0..7
  #pragma unroll
  for (int r16o = 0; r16o < 2; ++r16o) {
    int row = r16o * 16 + (fl & 15);
    int k0 = fk * 32 + (fl >> 4) * 8;
    float4 xa = *(const float4*)&Ct[row][k0];
    float4 xb = *(const float4*)&Ct[row][k0 + 4];
    short8 H, L;
    H[0] = f2bf(xa.x); H[1] = f2bf(xa.y); H[2] = f2bf(xa.z); H[3] = f2bf(xa.w);
    H[4] = f2bf(xb.x); H[5] = f2bf(xb.y); H[6] = f2bf(xb.z); H[7] = f2bf(xb.w);
    L[0] = f2bf(xa.x - bf2f(H[0])); L[1] = f2bf(xa.y - bf2f(H[1]));
    L[2] = f2bf(xa.z - bf2f(H[2])); L[3] = f2bf(xa.w - bf2f(H[3]));
    L[4] = f2bf(xb.x - bf2f(H[4])); L[5] = f2bf(xb.y - bf2f(H[5]));
    L[6] = f2bf(xb.z - bf2f(H[6])); L[7] = f2bf(xb.w - bf2f(H[7]));
    size_t u = ((size_t)((r16b + r16o) * 8 + fk) * 2) * 512 + (size_t)fl * 8;
    *(short8*)(Af + u) = H;
    *(short8*)(Af + u + 512) = L;
    *(short8*)(hg + (size_t)(rb + row) * DD + k0) = H;
  }
}

// ---------------------------------------------------------------- decode (reads bf16 hg)
__global__ __launch_bounds__(256) void kDec(const short* __restrict__ hg,
                                            const int* __restrict__ aidx,
                                            const float* __restrict__ W4,
                                            const float* __restrict__ W5,
                                            float* __restrict__ Q) {
  __shared__ float tmp[4];
  int b = blockIdx.x, j = threadIdx.x;
  float s = blockSum256(bf2f(hg[(size_t)(NN + b) * DD + j]) * W4[j], tmp);
  int a = aidx[b];
  float za = bf2f(hg[(size_t)a * DD + j]);
  float q = blockSum256(fmaxf(za * s, 0.f) * W5[j], tmp);
  if (j == 0) Q[b] = q;
}

// ---------------------------------------------------------------- launcher
extern "C" void kernel_launch(void* const* d_in, const int* in_sizes, int n_in,
                              void* d_out, int out_size, void* d_ws, size_t ws_size,
                              hipStream_t stream) {
  (void)in_sizes; (void)n_in; (void)out_size; (void)ws_size;
  const int*   edge_src = (const int*)d_in[0];
  const int*   edge_dst = (const int*)d_in[1];
  const float* edge_w   = (const float*)d_in[2];
  const int*   bassign  = (const int*)d_in[3];
  const int*   aidx     = (const int*)d_in[4];
  const float* Xf       = (const float*)d_in[5];
  const float* Xs       = (const float*)d_in[6];
  const float* W1       = (const float*)d_in[7];
  const float* W2       = (const float*)d_in[8];
  const float* W3       = (const float*)d_in[9];
  const float* linW     = (const float*)d_in[10];
  const float* linB     = (const float*)d_in[11];
  const float* W4       = (const float*)d_in[12];
  const float* W5       = (const float*)d_in[13];
  float* Q = (float*)d_out;

  char* base = (char*)d_ws;
  const size_t NB = (size_t)NT * DD * 4;   // 20.5 MB (split-fragment plane-pair bytes)
  short* hg   = (short*)(base);            // NB/2: bf16 h, in-place across depths
  short* Af   = (short*)(base + NB / 2);   // NB: split A-fragments, in-place
  short* Avf  = (short*)(base + NB / 2 + NB);  // NB: split hnv-fragments
  size_t o = NB / 2 + 2 * NB;
  short* Bf   = (short*)(base + o); o += (size_t)DD * 512 * 2 * 2;  // 512 KB, fragment order
  long long* sedge = (long long*)(base + o); o += (size_t)EE * 8;
  int*   snode= (int*)(base + o);   o += (size_t)NN * 4;
  int*   rank = (int*)(base + o);   o += (size_t)EE * 4;
  int*   rankB= (int*)(base + o);   o += (size_t)NN * 4;
  int*   offn = (int*)(base + o);   o += (size_t)(NN + 4) * 4;
  int*   offb = (int*)(base + o);   o += (size_t)(BB + 4) * 4;
  int*   curn = (int*)(base + o);   o += (size_t)NN * 4;
  int*   curb = (int*)(base + o);   o += (size_t)BB * 4;   // contiguous with curn

  hipMemsetAsync(curn, 0, (size_t)(NN + BB) * 4, stream);

  kPre<<<NCB + 512 + NT / 16, 256, 0, stream>>>(Xf, Xs, W1, hg, Af,
                                                edge_dst, bassign, curn, curb,
                                                rank, rankB,
                                                W2, W3, linW, Bf);
  kScan<<<1, 1024, 0, stream>>>(curn, offn, curb, offb);
  kPlace<<<(EE + 255) / 256, 256, 0, stream>>>(edge_src, edge_dst, edge_w, bassign,
                                               offn, offb, rank, rankB, sedge, snode);
  for (int d = 0; d < DEPTH; d++) {
    kAgg<<<4 * (NT / 8), 512, 0, stream>>>(hg, offn, sedge, offb, snode, Avf);
    kUpdM<<<NT / TRU, 512, 0, stream>>>(Af, Avf, Bf, linB, hg);
  }
  kDec<<<BB, 256, 0, stream>>>(hg, aidx, W4, W5, Q);
}

// Round 4
// 340.982 us; speedup vs baseline: 1.2390x; 1.2390x over previous
//
#include <hip/hip_runtime.h>

#define NN 20000
#define EE 320000
#define BB 64
#define DD 256
#define DEPTH 3
#define NT (NN + BB)   // h rows + hs rows appended (NT = 20064 = 16*1254 = 32*627 = 8*2508)

typedef __attribute__((ext_vector_type(8))) short short8;
typedef __attribute__((ext_vector_type(4))) float floatx4;

// ---------------------------------------------------------------- bf16 split helpers
__device__ __forceinline__ short f2bf(float x) {
  union { float f; unsigned u; } v; v.f = x;
  unsigned r = v.u + 0x7fffu + ((v.u >> 16) & 1u);  // RNE
  return (short)(r >> 16);
}
__device__ __forceinline__ float bf2f(short s) {
  union { unsigned u; float f; } v; v.u = ((unsigned)(unsigned short)s) << 16;
  return v.f;
}

// ---------------------------------------------------------------- fragment-order split store
// A-fragment layout: Af[(((row>>4)*8 + kc)*2 + plane)*512 + (kg*16 + (row&15))*8 + kel]
// (shorts; plane 0 = hi, 1 = lo; kc = k>>5, kg = (k>>3)&3, kel = k&7). A wave's 16x32
// fragment is ONE contiguous coalesced 1KB load in kUpdM.
// storeFragRow8: 8 consecutive cols (c0 % 8 == 0) of one row -> two 16B stores.
__device__ __forceinline__ void storeFragRow8(short* __restrict__ P, int row, int c0,
                                              const float* a) {
  short8 H, L;
  #pragma unroll
  for (int k = 0; k < 8; k++) {
    short hh = f2bf(a[k]);
    H[k] = hh;
    L[k] = f2bf(a[k] - bf2f(hh));
  }
  int kc = c0 >> 5, kg = (c0 >> 3) & 3;
  size_t u = ((size_t)((row >> 4) * 8 + kc) * 2) * 512 + (size_t)(kg * 16 + (row & 15)) * 8;
  *(short8*)(P + u) = H;
  *(short8*)(P + u + 512) = L;
}

// ---------------------------------------------------------------- reductions
__device__ __forceinline__ float blockSum256(float v, float* tmp) {
  #pragma unroll
  for (int o = 32; o > 0; o >>= 1) v += __shfl_down(v, o, 64);
  if ((threadIdx.x & 63) == 0) tmp[threadIdx.x >> 6] = v;
  __syncthreads();
  float r = tmp[0] + tmp[1] + tmp[2] + tmp[3];
  __syncthreads();
  return r;
}

// ---------------------------------------------------------------- kPre: rank atomics + kM + encode
// SINGLE atomic pass over edges (round-13). B in MFMA-fragment order (round-15/16).
// Encode 16-rows-per-block with LDS transpose -> coalesced Af writes (round-19).
#define NCB ((EE + 255) / 256)   // 1250
__global__ __launch_bounds__(256) void kPre(const float* __restrict__ X,
                                            const float* __restrict__ Xs,
                                            const float* __restrict__ W1,
                                            short* __restrict__ hg,
                                            short* __restrict__ Af,
                                            const int* __restrict__ dst,
                                            const int* __restrict__ bassign,
                                            int* curn, int* curb,
                                            int* __restrict__ rank,
                                            int* __restrict__ rankB,
                                            const float* __restrict__ W2,
                                            const float* __restrict__ W3,
                                            const float* __restrict__ linW,
                                            short* __restrict__ Bf) {
  __shared__ int hb[64], rs[64], hc[64];
  __shared__ __align__(16) short Hs[16][264];   // 264: stride 132 dwords %32 = 4 -> <=2-way
  __shared__ __align__(16) short Ls[16][264];
  int bid = blockIdx.x, j = threadIdx.x;
  if (bid < NCB) {
    if (j < 64) { hb[j] = 0; hc[j] = 0; }
    __syncthreads();
    int t = bid * 256 + j;
    int b = -1;
    if (t < NN) { b = bassign[t]; atomicAdd(&hb[b], 1); }
    __syncthreads();
    if (j < 64 && hb[j] > 0) rs[j] = atomicAdd(&curb[j], hb[j]);
    __syncthreads();
    if (t < NN) rankB[t] = rs[b] + atomicAdd(&hc[b], 1);
    if (t < EE) rank[t] = atomicAdd(&curn[dst[t]], 1);
  } else if (bid < NCB + 512) {
    // ---- M2 = W2 @ linW[0:256,:], M3 = W3 @ linW[256:512,:], fragment-order split
    int i = (bid - NCB) & 255;
    bool second = (bid - NCB) >= 256;
    const float* W = second ? W3 : W2;
    const float* L = linW + (second ? DD * DD : 0);
    float acc = 0.f;
    #pragma unroll 4
    for (int k = 0; k < DD; k++) acc = fmaf(W[i * DD + k], L[k * DD + j], acc);
    short hi = f2bf(acc);
    short lo = f2bf(acc - bf2f(hi));
    int kk = second ? (DD + i) : i;          // k index in B' (0..511)
    int kc = kk >> 5, kg = (kk >> 3) & 3, kel = kk & 7;
    int n16 = j >> 4, m16 = j & 15;
    size_t idx = ((size_t)(kc * 16 + n16) * 2) * 512 + (kg * 16 + m16) * 8 + kel;
    Bf[idx] = hi;
    Bf[idx + 512] = lo;
  } else {
    // ---- encode: 16 rows per block, 16 threads/row x 16 cols/thread
    int rg = bid - NCB - 512;        // row-group 0..1253
    int rl = j >> 4;                 // row-in-group 0..15 (16 lanes each, shfl<16 safe)
    int ci = j & 15;
    int r = rg * 16 + rl;
    int c0 = ci * 16;
    const float* x = (r < NN) ? (X + (size_t)r * 2) : (Xs + (size_t)(r - NN) * 2);
    float x0 = x[0], x1 = x[1];
    float v[16];
    float ss = 0.f;
    #pragma unroll
    for (int q = 0; q < 4; q++) {
      float4 wa = *(const float4*)(W1 + c0 + q * 4);
      float4 wb = *(const float4*)(W1 + DD + c0 + q * 4);
      float a0 = fmaxf(fmaf(x0, wa.x, x1 * wb.x), 0.f);
      float a1 = fmaxf(fmaf(x0, wa.y, x1 * wb.y), 0.f);
      float a2 = fmaxf(fmaf(x0, wa.z, x1 * wb.z), 0.f);
      float a3 = fmaxf(fmaf(x0, wa.w, x1 * wb.w), 0.f);
      v[q * 4 + 0] = a0; v[q * 4 + 1] = a1; v[q * 4 + 2] = a2; v[q * 4 + 3] = a3;
      ss = fmaf(a0, a0, ss); ss = fmaf(a1, a1, ss);
      ss = fmaf(a2, a2, ss); ss = fmaf(a3, a3, ss);
    }
    #pragma unroll
    for (int o = 1; o < 16; o <<= 1) ss += __shfl_xor(ss, o, 64);
    float inv = 1.f / fmaxf(sqrtf(ss), 1e-12f);
    short8 H0, H1, L0, L1;
    #pragma unroll
    for (int k = 0; k < 8; k++) {
      float s0 = v[k] * inv;
      float s1 = v[8 + k] * inv;
      short h0 = f2bf(s0), h1 = f2bf(s1);
      H0[k] = h0; H1[k] = h1;
      L0[k] = f2bf(s0 - bf2f(h0)); L1[k] = f2bf(s1 - bf2f(h1));
    }
    *(short8*)(hg + (size_t)r * DD + c0)     = H0;
    *(short8*)(hg + (size_t)r * DD + c0 + 8) = H1;
    *(short8*)&Hs[rl][c0] = H0;  *(short8*)&Hs[rl][c0 + 8] = H1;
    *(short8*)&Ls[rl][c0] = L0;  *(short8*)&Ls[rl][c0 + 8] = L1;
    __syncthreads();
    // ---- coalesced fragment write: thread j covers fragment kc=j>>5, positions j&31, +32
    int kc = j >> 5, p0 = j & 31;
    #pragma unroll
    for (int half = 0; half < 2; half++) {
      int p = p0 + half * 32;
      int prow = p & 15, kg = p >> 4;
      size_t ub = ((size_t)(rg * 8 + kc) * 2) * 512 + (size_t)p * 8;
      *(short8*)(Af + ub)       = *(const short8*)&Hs[prow][kc * 32 + kg * 8];
      *(short8*)(Af + ub + 512) = *(const short8*)&Ls[prow][kc * 32 + kg * 8];
    }
  }
}

// ---------------------------------------------------------------- CSR scan (counts live in curn/curb)
__global__ __launch_bounds__(1024) void kScan(const int* __restrict__ curn,
                                              int* offn,
                                              const int* __restrict__ curb,
                                              int* offb) {
  __shared__ int sums[1024];
  int t = threadIdx.x;
  const int CH = 20;  // 1024*20 = 20480 >= NN
  int base = t * CH;
  int local[CH];
  int s = 0;
  #pragma unroll
  for (int i = 0; i < CH; i++) {
    int idx = base + i;
    int v = (idx < NN) ? curn[idx] : 0;
    local[i] = s;
    s += v;
  }
  sums[t] = s;
  __syncthreads();
  for (int o = 1; o < 1024; o <<= 1) {
    int x = (t >= o) ? sums[t - o] : 0;
    __syncthreads();
    sums[t] += x;
    __syncthreads();
  }
  int excl = sums[t] - s;
  #pragma unroll
  for (int i = 0; i < CH; i++) {
    int idx = base + i;
    if (idx < NN) offn[idx] = excl + local[i];
  }
  if (t == 1023) offn[NN] = sums[1023];
  // batch offsets: 64-lane shuffle scan (first wave)
  if (t < 64) {
    int v = curb[t];
    int incl = v;
    #pragma unroll
    for (int o = 1; o < 64; o <<= 1) {
      int x = __shfl_up(incl, o, 64);
      if (t >= o) incl += x;
    }
    offb[t] = incl - v;
    if (t == 63) offb[BB] = incl;
  }
}

// ---------------------------------------------------------------- kPlace: rank -> position, no atomics
__global__ __launch_bounds__(256) void kPlace(const int* __restrict__ src,
                                              const int* __restrict__ dst,
                                              const float* __restrict__ w,
                                              const int* __restrict__ bassign,
                                              const int* __restrict__ offn,
                                              const int* __restrict__ offb,
                                              const int* __restrict__ rank,
                                              const int* __restrict__ rankB,
                                              long long* sedge, int* snode) {
  int t = blockIdx.x * 256 + threadIdx.x;
  if (t < EE) {
    unsigned long long e = (unsigned long long)(unsigned)src[t]
                         | ((unsigned long long)(unsigned)__float_as_int(w[t]) << 32);
    sedge[offn[dst[t]] + rank[t]] = (long long)e;
  }
  if (t < NN) snode[offb[bassign[t]] + rankB[t]] = t;
}

// ---------------------------------------------------------------- aggregation (XCD-sliced, 8 waves = 8 nodes)
// round-19: bf16 hg gathers (4 slices x 64 cols, one 128B line per edge-slice);
// slice = bid&3 pins each XCD to one slice -> 2.56MB/XCD, L2-resident.
// round-21: NT loads REVERTED (round-3 evidence: gfx950 `nt` streams in L2 too ->
// L3-latency round trips, +10us on both hot kernels).
#define ECAP 1024   // staged edges per chunk (8 KB)
__global__ __launch_bounds__(512) void kAgg(const short* __restrict__ hg,
                                            const int* __restrict__ offn,
                                            const long long* __restrict__ sedge,
                                            const int* __restrict__ offb,
                                            const int* __restrict__ snode,
                                            short* __restrict__ Avf) {
  __shared__ __align__(16) long long Led[ECAP];
  int bid = blockIdx.x;
  int slice = bid & 3, group = bid >> 2;      // group 0..2507
  int t = threadIdx.x;
  int w = t >> 6, lane = t & 63;
  int eg = lane >> 3;          // edge group 0..7
  int pc = lane & 7;           // 16B piece 0..7
  int colB = slice * 64 + pc * 8;             // 8 bf16 cols per lane
  float acc[8];
  #pragma unroll
  for (int jj = 0; jj < 8; jj++) acc[jj] = 0.f;

  if (group < 8) {
    // ---- batch rows: nodes 0..63 (8 per block), snode index list (weight 1)
    int b0 = group * 8;
    int s0 = offb[b0], e0 = offb[b0 + 8];
    int sW = offb[b0 + w], eW = offb[b0 + w + 1];
    int* Li = (int*)Led;
    for (int base = s0; base < e0; base += 2 * ECAP) {
      int cnt = min(e0 - base, 2 * ECAP);
      __syncthreads();
      for (int i = t; i < cnt; i += 512) Li[i] = snode[base + i];
      __syncthreads();
      int lo = max(sW, base), hi = min(eW, base + cnt);
      for (int i = lo; i < hi; i += 16) {
        int i0 = i + eg, i1 = i + 8 + eg;
        int n0 = Li[min(i0, hi - 1) - base];
        int n1 = Li[min(i1, hi - 1) - base];
        float w0 = (i0 < hi) ? 1.f : 0.f;
        float w1 = (i1 < hi) ? 1.f : 0.f;
        short8 a0 = *(const short8*)(hg + (size_t)n0 * DD + colB);
        short8 a1 = *(const short8*)(hg + (size_t)n1 * DD + colB);
        #pragma unroll
        for (int jj = 0; jj < 8; jj++)
          acc[jj] = fmaf(w1, bf2f(a1[jj]), fmaf(w0, bf2f(a0[jj]), acc[jj]));
      }
    }
    #pragma unroll
    for (int o = 8; o < 64; o <<= 1)
      #pragma unroll
      for (int jj = 0; jj < 8; jj++) acc[jj] += __shfl_xor(acc[jj], o, 64);
    if (eg == 0) storeFragRow8(Avf, NN + b0 + w, colB, acc);
  } else {
    // ---- edge nodes, 8 per block
    int first = (group - 8) * 8;
    int s0 = offn[first], e0 = offn[first + 8];
    int sW = offn[first + w], eW = offn[first + w + 1];
    for (int base = s0; base < e0; base += ECAP) {
      int cnt = min(e0 - base, ECAP);
      __syncthreads();
      for (int i = t; i < cnt; i += 512) Led[i] = sedge[base + i];
      __syncthreads();
      int lo = max(sW, base), hi = min(eW, base + cnt);
      for (int i = lo; i < hi; i += 16) {
        int i0 = i + eg, i1 = i + 8 + eg;
        long long e0v = Led[min(i0, hi - 1) - base];
        long long e1v = Led[min(i1, hi - 1) - base];
        float w0 = (i0 < hi) ? __int_as_float((int)(e0v >> 32)) : 0.f;
        float w1 = (i1 < hi) ? __int_as_float((int)(e1v >> 32)) : 0.f;
        unsigned r0 = (unsigned)(e0v & 0xffffffffLL);
        unsigned r1 = (unsigned)(e1v & 0xffffffffLL);
        short8 a0 = *(const short8*)(hg + (size_t)r0 * DD + colB);
        short8 a1 = *(const short8*)(hg + (size_t)r1 * DD + colB);
        #pragma unroll
        for (int jj = 0; jj < 8; jj++)
          acc[jj] = fmaf(w1, bf2f(a1[jj]), fmaf(w0, bf2f(a0[jj]), acc[jj]));
      }
    }
    #pragma unroll
    for (int o = 8; o < 64; o <<= 1)
      #pragma unroll
      for (int jj = 0; jj < 8; jj++) acc[jj] += __shfl_xor(acc[jj], o, 64);
    if (eg == 0) storeFragRow8(Avf, first + w, colB, acc);
  }
}

// ---------------------------------------------------------------- MFMA dual-GEMM + fused l2norm
// round-21: B stream moved to the global_load_lds DMA path. r2's ~38us was
// line-service-bound on the VGPR-return path (~9cyc/line/CU); m97/m151 evidence:
// DMA staging sustains ~1 line/3cyc/CU. Per-wave double-buffered stage (4KB/kc),
// NO __syncthreads in the main loop (waves free-run; per-wave counted vmcnt(4):
// drains stage(kc)+A(kc), leaves the 4 just-issued DMAs in flight). A-fragments
// software-pipelined one kc ahead in VGPRs (compile-time-unrolled double regs).
// Epilogue Ct OVERLAYS the stage LDS -- first Ct touch is after the ssq
// __syncthreads, by which every wave has executed its final vmcnt(0). 65KB LDS
// -> 2 blocks/CU.
#define TRU 32
__global__ __launch_bounds__(512) void kUpdM(short* __restrict__ Af,
                                             const short* __restrict__ Avf,
                                             const short* __restrict__ Bf,
                                             const float* __restrict__ lb,
                                             short* __restrict__ hg) {
  __shared__ __align__(16) short Bst[8][2][4][512];   // [wave][buf][ct*2+plane][512] = 64KB
  __shared__ float ssq[8][TRU];
  float (*Ct)[260] = (float(*)[260]) & Bst[0][0][0][0];   // epilogue overlay (33.3KB)
  const int t = threadIdx.x;
  const int rb = blockIdx.x * TRU;
  const int wid = t >> 6;          // 0..7
  const int lane = t & 63;
  const int wc = wid * 32;         // wave col offset (8 waves cover 256 cols)
  const int m16 = lane & 15;
  const int kg = lane >> 4;        // 0..3
  const int r16b = rb >> 4;

  floatx4 acc[2][2];
  #pragma unroll
  for (int ct = 0; ct < 2; ct++) {
    float b = lb[wc + ct * 16 + m16];
    #pragma unroll
    for (int rt = 0; rt < 2; rt++) acc[rt][ct] = (floatx4){b, b, b, b};
  }

  short8 aH[2][2], aL[2][2];       // [kc&1][rt] -- static indices after full unroll

  // prologue: stage kc=0, load A(0)
  #pragma unroll
  for (int f = 0; f < 4; f++) {
    const short* g = Bf + ((size_t)((0 * 16 + wid * 2) * 2 + f)) * 512 + lane * 8;
    __builtin_amdgcn_global_load_lds((const __attribute__((address_space(1))) unsigned int*)g,
                                     (__attribute__((address_space(3))) unsigned int*)&Bst[wid][0][f][0],
                                     16, 0, 0);
  }
  #pragma unroll
  for (int rt = 0; rt < 2; rt++) {
    const short* ap = Af + ((size_t)((r16b + rt) * 8 + 0) * 2) * 512 + lane * 8;
    aH[0][rt] = *(const short8*)ap;
    aL[0][rt] = *(const short8*)(ap + 512);
  }

  #pragma unroll
  for (int kc = 0; kc < 16; kc++) {
    const int buf = kc & 1;
    if (kc < 15) {
      #pragma unroll
      for (int f = 0; f < 4; f++) {
        const short* g = Bf + ((size_t)(((kc + 1) * 16 + wid * 2) * 2 + f)) * 512 + lane * 8;
        __builtin_amdgcn_global_load_lds((const __attribute__((address_space(1))) unsigned int*)g,
                                         (__attribute__((address_space(3))) unsigned int*)&Bst[wid][buf ^ 1][f][0],
                                         16, 0, 0);
      }
      asm volatile("s_waitcnt vmcnt(4)" ::: "memory");
    } else {
      asm volatile("s_waitcnt vmcnt(0)" ::: "memory");
    }
    __builtin_amdgcn_sched_barrier(0);
    if (kc < 15) {
      const short* Ab = ((kc + 1) < 8) ? Af : Avf;
      const int kcl = (kc + 1) & 7;
      #pragma unroll
      for (int rt = 0; rt < 2; rt++) {
        const short* ap = Ab + ((size_t)((r16b + rt) * 8 + kcl) * 2) * 512 + lane * 8;
        aH[(kc + 1) & 1][rt] = *(const short8*)ap;
        aL[(kc + 1) & 1][rt] = *(const short8*)(ap + 512);
      }
    }
    #pragma unroll
    for (int ct = 0; ct < 2; ct++) {
      short8 bh = *(const short8*)&Bst[wid][buf][ct * 2 + 0][lane * 8];
      short8 bl = *(const short8*)&Bst[wid][buf][ct * 2 + 1][lane * 8];
      #pragma unroll
      for (int rt = 0; rt < 2; rt++) {
        acc[rt][ct] = __builtin_amdgcn_mfma_f32_16x16x32_bf16(aH[buf][rt], bh, acc[rt][ct], 0, 0, 0);
        acc[rt][ct] = __builtin_amdgcn_mfma_f32_16x16x32_bf16(aH[buf][rt], bl, acc[rt][ct], 0, 0, 0);
        acc[rt][ct] = __builtin_amdgcn_mfma_f32_16x16x32_bf16(aL[buf][rt], bh, acc[rt][ct], 0, 0, 0);
      }
    }
  }

  // ---- epilogue: relu + row l2norm (C/D: col=lane&15, row=(lane>>4)*4+reg)
  float p[2][4];
  #pragma unroll
  for (int rt = 0; rt < 2; rt++)
    #pragma unroll
    for (int reg = 0; reg < 4; reg++) {
      float s = 0.f;
      #pragma unroll
      for (int ct = 0; ct < 2; ct++) {
        float x = fmaxf(acc[rt][ct][reg], 0.f);
        s = fmaf(x, x, s);
      }
      p[rt][reg] = s;
    }
  #pragma unroll
  for (int o = 1; o < 16; o <<= 1)
    #pragma unroll
    for (int rt = 0; rt < 2; rt++)
      #pragma unroll
      for (int reg = 0; reg < 4; reg++)
        p[rt][reg] += __shfl_xor(p[rt][reg], o, 64);
  if (m16 == 0) {
    #pragma unroll
    for (int rt = 0; rt < 2; rt++)
      #pragma unroll
      for (int reg = 0; reg < 4; reg++)
        ssq[wid][rt * 16 + kg * 4 + reg] = p[rt][reg];
  }
  __syncthreads();   // after this barrier all waves are past their last Bst read
  #pragma unroll
  for (int rt = 0; rt < 2; rt++) {
    #pragma unroll
    for (int reg = 0; reg < 4; reg++) {
      int row = rt * 16 + kg * 4 + reg;
      float ss = 0.f;
      #pragma unroll
      for (int ww = 0; ww < 8; ww++) ss += ssq[ww][row];
      float inv = 1.f / fmaxf(sqrtf(ss), 1e-12f);
      #pragma unroll
      for (int ct = 0; ct < 2; ct++) {
        int col = wc + ct * 16 + m16;
        Ct[row][col] = fmaxf(acc[rt][ct][reg], 0.f) * inv;
      }
    }
  }
  __syncthreads();
  // ---- fragment-order split write-back (in-place Af) + bf16 hg, 16B stores
  const int fl = lane;                 // lane-in-fragment
  const int fk = wid;                  // kc 0..7
  #pragma unroll
  for (int r16o = 0; r16o < 2; ++r16o) {
    int row = r16o * 16 + (fl & 15);
    int k0 = fk * 32 + (fl >> 4) * 8;
    float4 xa = *(const float4*)&Ct[row][k0];
    float4 xb = *(const float4*)&Ct[row][k0 + 4];
    short8 H, L;
    H[0] = f2bf(xa.x); H[1] = f2bf(xa.y); H[2] = f2bf(xa.z); H[3] = f2bf(xa.w);
    H[4] = f2bf(xb.x); H[5] = f2bf(xb.y); H[6] = f2bf(xb.z); H[7] = f2bf(xb.w);
    L[0] = f2bf(xa.x - bf2f(H[0])); L[1] = f2bf(xa.y - bf2f(H[1]));
    L[2] = f2bf(xa.z - bf2f(H[2])); L[3] = f2bf(xa.w - bf2f(H[3]));
    L[4] = f2bf(xb.x - bf2f(H[4])); L[5] = f2bf(xb.y - bf2f(H[5]));
    L[6] = f2bf(xb.z - bf2f(H[6])); L[7] = f2bf(xb.w - bf2f(H[7]));
    size_t u = ((size_t)((r16b + r16o) * 8 + fk) * 2) * 512 + (size_t)fl * 8;
    *(short8*)(Af + u) = H;
    *(short8*)(Af + u + 512) = L;
    *(short8*)(hg + (size_t)(rb + row) * DD + k0) = H;
  }
}

// ---------------------------------------------------------------- decode (reads bf16 hg)
__global__ __launch_bounds__(256) void kDec(const short* __restrict__ hg,
                                            const int* __restrict__ aidx,
                                            const float* __restrict__ W4,
                                            const float* __restrict__ W5,
                                            float* __restrict__ Q) {
  __shared__ float tmp[4];
  int b = blockIdx.x, j = threadIdx.x;
  float s = blockSum256(bf2f(hg[(size_t)(NN + b) * DD + j]) * W4[j], tmp);
  int a = aidx[b];
  float za = bf2f(hg[(size_t)a * DD + j]);
  float q = blockSum256(fmaxf(za * s, 0.f) * W5[j], tmp);
  if (j == 0) Q[b] = q;
}

// ---------------------------------------------------------------- launcher
extern "C" void kernel_launch(void* const* d_in, const int* in_sizes, int n_in,
                              void* d_out, int out_size, void* d_ws, size_t ws_size,
                              hipStream_t stream) {
  (void)in_sizes; (void)n_in; (void)out_size; (void)ws_size;
  const int*   edge_src = (const int*)d_in[0];
  const int*   edge_dst = (const int*)d_in[1];
  const float* edge_w   = (const float*)d_in[2];
  const int*   bassign  = (const int*)d_in[3];
  const int*   aidx     = (const int*)d_in[4];
  const float* Xf       = (const float*)d_in[5];
  const float* Xs       = (const float*)d_in[6];
  const float* W1       = (const float*)d_in[7];
  const float* W2       = (const float*)d_in[8];
  const float* W3       = (const float*)d_in[9];
  const float* linW     = (const float*)d_in[10];
  const float* linB     = (const float*)d_in[11];
  const float* W4       = (const float*)d_in[12];
  const float* W5       = (const float*)d_in[13];
  float* Q = (float*)d_out;

  char* base = (char*)d_ws;
  const size_t NB = (size_t)NT * DD * 4;   // 20.5 MB (split-fragment plane-pair bytes)
  short* hg   = (short*)(base);            // NB/2: bf16 h, in-place across depths
  short* Af   = (short*)(base + NB / 2);   // NB: split A-fragments, in-place
  short* Avf  = (short*)(base + NB / 2 + NB);  // NB: split hnv-fragments
  size_t o = NB / 2 + 2 * NB;
  short* Bf   = (short*)(base + o); o += (size_t)DD * 512 * 2 * 2;  // 512 KB, fragment order
  long long* sedge = (long long*)(base + o); o += (size_t)EE * 8;
  int*   snode= (int*)(base + o);   o += (size_t)NN * 4;
  int*   rank = (int*)(base + o);   o += (size_t)EE * 4;
  int*   rankB= (int*)(base + o);   o += (size_t)NN * 4;
  int*   offn = (int*)(base + o);   o += (size_t)(NN + 4) * 4;
  int*   offb = (int*)(base + o);   o += (size_t)(BB + 4) * 4;
  int*   curn = (int*)(base + o);   o += (size_t)NN * 4;
  int*   curb = (int*)(base + o);   o += (size_t)BB * 4;   // contiguous with curn

  hipMemsetAsync(curn, 0, (size_t)(NN + BB) * 4, stream);

  kPre<<<NCB + 512 + NT / 16, 256, 0, stream>>>(Xf, Xs, W1, hg, Af,
                                                edge_dst, bassign, curn, curb,
                                                rank, rankB,
                                                W2, W3, linW, Bf);
  kScan<<<1, 1024, 0, stream>>>(curn, offn, curb, offb);
  kPlace<<<(EE + 255) / 256, 256, 0, stream>>>(edge_src, edge_dst, edge_w, bassign,
                                               offn, offb, rank, rankB, sedge, snode);
  for (int d = 0; d < DEPTH; d++) {
    kAgg<<<4 * (NT / 8), 512, 0, stream>>>(hg, offn, sedge, offb, snode, Avf);
    kUpdM<<<NT / TRU, 512, 0, stream>>>(Af, Avf, Bf, linB, hg);
  }
  kDec<<<BB, 256, 0, stream>>>(hg, aidx, W4, W5, Q);
}

// Round 5
// 329.018 us; speedup vs baseline: 1.2840x; 1.0364x over previous
//
#include <hip/hip_runtime.h>

#define NN 20000
#define EE 320000
#define BB 64
#define DD 256
#define DEPTH 3
#define NT (NN + BB)   // h rows + hs rows appended (NT = 20064 = 16*1254 = 48*418 = 8*2508)

typedef __attribute__((ext_vector_type(8))) short short8;
typedef __attribute__((ext_vector_type(4))) float floatx4;

// ---------------------------------------------------------------- bf16 split helpers
__device__ __forceinline__ short f2bf(float x) {
  union { float f; unsigned u; } v; v.f = x;
  unsigned r = v.u + 0x7fffu + ((v.u >> 16) & 1u);  // RNE
  return (short)(r >> 16);
}
__device__ __forceinline__ float bf2f(short s) {
  union { unsigned u; float f; } v; v.u = ((unsigned)(unsigned short)s) << 16;
  return v.f;
}

// ---------------------------------------------------------------- fragment-order split store
// A-fragment layout: Af[(((row>>4)*8 + kc)*2 + plane)*512 + (kg*16 + (row&15))*8 + kel]
// (shorts; plane 0 = hi, 1 = lo; kc = k>>5, kg = (k>>3)&3, kel = k&7). A wave's 16x32
// fragment is ONE contiguous coalesced 1KB load in kUpdM.
__device__ __forceinline__ void storeFragRow8(short* __restrict__ P, int row, int c0,
                                              const float* a) {
  short8 H, L;
  #pragma unroll
  for (int k = 0; k < 8; k++) {
    short hh = f2bf(a[k]);
    H[k] = hh;
    L[k] = f2bf(a[k] - bf2f(hh));
  }
  int kc = c0 >> 5, kg = (c0 >> 3) & 3;
  size_t u = ((size_t)((row >> 4) * 8 + kc) * 2) * 512 + (size_t)(kg * 16 + (row & 15)) * 8;
  *(short8*)(P + u) = H;
  *(short8*)(P + u + 512) = L;
}

// ---------------------------------------------------------------- reductions
__device__ __forceinline__ float blockSum256(float v, float* tmp) {
  #pragma unroll
  for (int o = 32; o > 0; o >>= 1) v += __shfl_down(v, o, 64);
  if ((threadIdx.x & 63) == 0) tmp[threadIdx.x >> 6] = v;
  __syncthreads();
  float r = tmp[0] + tmp[1] + tmp[2] + tmp[3];
  __syncthreads();
  return r;
}

// ---------------------------------------------------------------- kPre: rank atomics + kM + encode
// round-22: M-phase restructured 512 -> 64 blocks, 8 rows each, W rows staged in
// LDS. Old structure streamed ALL 256KB of the linW-half per block = 131MB of L2
// reads for a 67-MFLOP GEMM; now each L row is reused 8x -> 16MB. k-accumulation
// order unchanged -> M (and Bf) bit-identical.
#define NCB ((EE + 255) / 256)   // 1250
__global__ __launch_bounds__(256) void kPre(const float* __restrict__ X,
                                            const float* __restrict__ Xs,
                                            const float* __restrict__ W1,
                                            short* __restrict__ hg,
                                            short* __restrict__ Af,
                                            const int* __restrict__ dst,
                                            const int* __restrict__ bassign,
                                            int* curn, int* curb,
                                            int* __restrict__ rank,
                                            int* __restrict__ rankB,
                                            const float* __restrict__ W2,
                                            const float* __restrict__ W3,
                                            const float* __restrict__ linW,
                                            short* __restrict__ Bf) {
  __shared__ int hb[64], rs[64], hc[64];
  __shared__ __align__(16) short Hs[16][264];   // 264: stride 132 dwords %32 = 4 -> <=2-way
  __shared__ __align__(16) short Ls[16][264];
  __shared__ __align__(16) float Wl[8][DD];     // M-phase W rows (8KB)
  int bid = blockIdx.x, j = threadIdx.x;
  if (bid < NCB) {
    if (j < 64) { hb[j] = 0; hc[j] = 0; }
    __syncthreads();
    int t = bid * 256 + j;
    int b = -1;
    if (t < NN) { b = bassign[t]; atomicAdd(&hb[b], 1); }
    __syncthreads();
    if (j < 64 && hb[j] > 0) rs[j] = atomicAdd(&curb[j], hb[j]);
    __syncthreads();
    if (t < NN) rankB[t] = rs[b] + atomicAdd(&hc[b], 1);
    if (t < EE) rank[t] = atomicAdd(&curn[dst[t]], 1);
  } else if (bid < NCB + 64) {
    // ---- M' rows rbase..rbase+7 (M2 = W2 @ linW_top for rows<256, else M3)
    int rbase = (bid - NCB) * 8;                 // 0..504
    bool second = rbase >= 256;
    const float* W = second ? W3 : W2;
    const float* L = linW + (second ? DD * DD : 0);
    int i0 = second ? (rbase - 256) : rbase;
    // stage the 8 W rows into LDS (coalesced)
    for (int q = j; q < 8 * DD; q += 256) Wl[q >> 8][q & 255] = W[(size_t)(i0 + (q >> 8)) * DD + (q & 255)];
    __syncthreads();
    float acc[8];
    #pragma unroll
    for (int r = 0; r < 8; r++) acc[r] = 0.f;
    #pragma unroll 4
    for (int k = 0; k < DD; k++) {
      float lv = L[(size_t)k * DD + j];
      #pragma unroll
      for (int r = 0; r < 8; r++) acc[r] = fmaf(Wl[r][k], lv, acc[r]);
    }
    #pragma unroll
    for (int r = 0; r < 8; r++) {
      int kk = rbase + r;                        // row index in B' (0..511)
      short hi = f2bf(acc[r]);
      short lo = f2bf(acc[r] - bf2f(hi));
      int kc = kk >> 5, kg = (kk >> 3) & 3, kel = kk & 7;
      int n16 = j >> 4, m16 = j & 15;
      size_t idx = ((size_t)(kc * 16 + n16) * 2) * 512 + (kg * 16 + m16) * 8 + kel;
      Bf[idx] = hi;
      Bf[idx + 512] = lo;
    }
  } else {
    // ---- encode: 16 rows per block, 16 threads/row x 16 cols/thread
    int rg = bid - NCB - 64;         // row-group 0..1253
    int rl = j >> 4;                 // row-in-group 0..15 (16 lanes each, shfl<16 safe)
    int ci = j & 15;
    int r = rg * 16 + rl;
    int c0 = ci * 16;
    const float* x = (r < NN) ? (X + (size_t)r * 2) : (Xs + (size_t)(r - NN) * 2);
    float x0 = x[0], x1 = x[1];
    float v[16];
    float ss = 0.f;
    #pragma unroll
    for (int q = 0; q < 4; q++) {
      float4 wa = *(const float4*)(W1 + c0 + q * 4);
      float4 wb = *(const float4*)(W1 + DD + c0 + q * 4);
      float a0 = fmaxf(fmaf(x0, wa.x, x1 * wb.x), 0.f);
      float a1 = fmaxf(fmaf(x0, wa.y, x1 * wb.y), 0.f);
      float a2 = fmaxf(fmaf(x0, wa.z, x1 * wb.z), 0.f);
      float a3 = fmaxf(fmaf(x0, wa.w, x1 * wb.w), 0.f);
      v[q * 4 + 0] = a0; v[q * 4 + 1] = a1; v[q * 4 + 2] = a2; v[q * 4 + 3] = a3;
      ss = fmaf(a0, a0, ss); ss = fmaf(a1, a1, ss);
      ss = fmaf(a2, a2, ss); ss = fmaf(a3, a3, ss);
    }
    #pragma unroll
    for (int o = 1; o < 16; o <<= 1) ss += __shfl_xor(ss, o, 64);
    float inv = 1.f / fmaxf(sqrtf(ss), 1e-12f);
    short8 H0, H1, L0, L1;
    #pragma unroll
    for (int k = 0; k < 8; k++) {
      float s0 = v[k] * inv;
      float s1 = v[8 + k] * inv;
      short h0 = f2bf(s0), h1 = f2bf(s1);
      H0[k] = h0; H1[k] = h1;
      L0[k] = f2bf(s0 - bf2f(h0)); L1[k] = f2bf(s1 - bf2f(h1));
    }
    *(short8*)(hg + (size_t)r * DD + c0)     = H0;
    *(short8*)(hg + (size_t)r * DD + c0 + 8) = H1;
    *(short8*)&Hs[rl][c0] = H0;  *(short8*)&Hs[rl][c0 + 8] = H1;
    *(short8*)&Ls[rl][c0] = L0;  *(short8*)&Ls[rl][c0 + 8] = L1;
    __syncthreads();
    // ---- coalesced fragment write: thread j covers fragment kc=j>>5, positions j&31, +32
    int kc = j >> 5, p0 = j & 31;
    #pragma unroll
    for (int half = 0; half < 2; half++) {
      int p = p0 + half * 32;
      int prow = p & 15, kg = p >> 4;
      size_t ub = ((size_t)(rg * 8 + kc) * 2) * 512 + (size_t)p * 8;
      *(short8*)(Af + ub)       = *(const short8*)&Hs[prow][kc * 32 + kg * 8];
      *(short8*)(Af + ub + 512) = *(const short8*)&Ls[prow][kc * 32 + kg * 8];
    }
  }
}

// ---------------------------------------------------------------- CSR scan (counts live in curn/curb)
__global__ __launch_bounds__(1024) void kScan(const int* __restrict__ curn,
                                              int* offn,
                                              const int* __restrict__ curb,
                                              int* offb) {
  __shared__ int sums[1024];
  int t = threadIdx.x;
  const int CH = 20;  // 1024*20 = 20480 >= NN
  int base = t * CH;
  int local[CH];
  int s = 0;
  #pragma unroll
  for (int i = 0; i < CH; i++) {
    int idx = base + i;
    int v = (idx < NN) ? curn[idx] : 0;
    local[i] = s;
    s += v;
  }
  sums[t] = s;
  __syncthreads();
  for (int o = 1; o < 1024; o <<= 1) {
    int x = (t >= o) ? sums[t - o] : 0;
    __syncthreads();
    sums[t] += x;
    __syncthreads();
  }
  int excl = sums[t] - s;
  #pragma unroll
  for (int i = 0; i < CH; i++) {
    int idx = base + i;
    if (idx < NN) offn[idx] = excl + local[i];
  }
  if (t == 1023) offn[NN] = sums[1023];
  // batch offsets: 64-lane shuffle scan (first wave)
  if (t < 64) {
    int v = curb[t];
    int incl = v;
    #pragma unroll
    for (int o = 1; o < 64; o <<= 1) {
      int x = __shfl_up(incl, o, 64);
      if (t >= o) incl += x;
    }
    offb[t] = incl - v;
    if (t == 63) offb[BB] = incl;
  }
}

// ---------------------------------------------------------------- kPlace: rank -> position, no atomics
__global__ __launch_bounds__(256) void kPlace(const int* __restrict__ src,
                                              const int* __restrict__ dst,
                                              const float* __restrict__ w,
                                              const int* __restrict__ bassign,
                                              const int* __restrict__ offn,
                                              const int* __restrict__ offb,
                                              const int* __restrict__ rank,
                                              const int* __restrict__ rankB,
                                              long long* sedge, int* snode) {
  int t = blockIdx.x * 256 + threadIdx.x;
  if (t < EE) {
    unsigned long long e = (unsigned long long)(unsigned)src[t]
                         | ((unsigned long long)(unsigned)__float_as_int(w[t]) << 32);
    sedge[offn[dst[t]] + rank[t]] = (long long)e;
  }
  if (t < NN) snode[offb[bassign[t]] + rankB[t]] = t;
}

// ---------------------------------------------------------------- aggregation (XCD-sliced, 8 waves = 8 nodes)
// round-19: bf16 hg gathers (4 slices x 64 cols, one 128B line per edge-slice);
// round-21: NT loads REVERTED (gfx950 `nt` streams in L2 too -> L3 round trips).
#define ECAP 1024   // staged edges per chunk (8 KB)
__global__ __launch_bounds__(512) void kAgg(const short* __restrict__ hg,
                                            const int* __restrict__ offn,
                                            const long long* __restrict__ sedge,
                                            const int* __restrict__ offb,
                                            const int* __restrict__ snode,
                                            short* __restrict__ Avf) {
  __shared__ __align__(16) long long Led[ECAP];
  int bid = blockIdx.x;
  int slice = bid & 3, group = bid >> 2;      // group 0..2507
  int t = threadIdx.x;
  int w = t >> 6, lane = t & 63;
  int eg = lane >> 3;          // edge group 0..7
  int pc = lane & 7;           // 16B piece 0..7
  int colB = slice * 64 + pc * 8;             // 8 bf16 cols per lane
  float acc[8];
  #pragma unroll
  for (int jj = 0; jj < 8; jj++) acc[jj] = 0.f;

  if (group < 8) {
    // ---- batch rows: nodes 0..63 (8 per block), snode index list (weight 1)
    int b0 = group * 8;
    int s0 = offb[b0], e0 = offb[b0 + 8];
    int sW = offb[b0 + w], eW = offb[b0 + w + 1];
    int* Li = (int*)Led;
    for (int base = s0; base < e0; base += 2 * ECAP) {
      int cnt = min(e0 - base, 2 * ECAP);
      __syncthreads();
      for (int i = t; i < cnt; i += 512) Li[i] = snode[base + i];
      __syncthreads();
      int lo = max(sW, base), hi = min(eW, base + cnt);
      for (int i = lo; i < hi; i += 16) {
        int i0 = i + eg, i1 = i + 8 + eg;
        int n0 = Li[min(i0, hi - 1) - base];
        int n1 = Li[min(i1, hi - 1) - base];
        float w0 = (i0 < hi) ? 1.f : 0.f;
        float w1 = (i1 < hi) ? 1.f : 0.f;
        short8 a0 = *(const short8*)(hg + (size_t)n0 * DD + colB);
        short8 a1 = *(const short8*)(hg + (size_t)n1 * DD + colB);
        #pragma unroll
        for (int jj = 0; jj < 8; jj++)
          acc[jj] = fmaf(w1, bf2f(a1[jj]), fmaf(w0, bf2f(a0[jj]), acc[jj]));
      }
    }
    #pragma unroll
    for (int o = 8; o < 64; o <<= 1)
      #pragma unroll
      for (int jj = 0; jj < 8; jj++) acc[jj] += __shfl_xor(acc[jj], o, 64);
    if (eg == 0) storeFragRow8(Avf, NN + b0 + w, colB, acc);
  } else {
    // ---- edge nodes, 8 per block
    int first = (group - 8) * 8;
    int s0 = offn[first], e0 = offn[first + 8];
    int sW = offn[first + w], eW = offn[first + w + 1];
    for (int base = s0; base < e0; base += ECAP) {
      int cnt = min(e0 - base, ECAP);
      __syncthreads();
      for (int i = t; i < cnt; i += 512) Led[i] = sedge[base + i];
      __syncthreads();
      int lo = max(sW, base), hi = min(eW, base + cnt);
      for (int i = lo; i < hi; i += 16) {
        int i0 = i + eg, i1 = i + 8 + eg;
        long long e0v = Led[min(i0, hi - 1) - base];
        long long e1v = Led[min(i1, hi - 1) - base];
        float w0 = (i0 < hi) ? __int_as_float((int)(e0v >> 32)) : 0.f;
        float w1 = (i1 < hi) ? __int_as_float((int)(e1v >> 32)) : 0.f;
        unsigned r0 = (unsigned)(e0v & 0xffffffffLL);
        unsigned r1 = (unsigned)(e1v & 0xffffffffLL);
        short8 a0 = *(const short8*)(hg + (size_t)r0 * DD + colB);
        short8 a1 = *(const short8*)(hg + (size_t)r1 * DD + colB);
        #pragma unroll
        for (int jj = 0; jj < 8; jj++)
          acc[jj] = fmaf(w1, bf2f(a1[jj]), fmaf(w0, bf2f(a0[jj]), acc[jj]));
      }
    }
    #pragma unroll
    for (int o = 8; o < 64; o <<= 1)
      #pragma unroll
      for (int jj = 0; jj < 8; jj++) acc[jj] += __shfl_xor(acc[jj], o, 64);
    if (eg == 0) storeFragRow8(Avf, first + w, colB, acc);
  }
}

// ---------------------------------------------------------------- MFMA dual-GEMM + fused l2norm
// round-22: TRU 32 -> 48 (20064 = 48*418, exact; 1254 = 3*418 row-groups). Every
// block streams the full 512KB Bf, so rows/block up => B traffic/row down 1/3
// (320 -> 214 MB/dispatch); critical-path CUs go 3 blocks (1.5MB B) -> 2 blocks
// (1.0MB) for the same 96 rows. DMA double-buffer per-wave staging kept (r4: null
// vs reg loads, not negative). Ct[48][260] = 49.9KB still overlays Bst (64KB).
#define TRU 48
__global__ __launch_bounds__(512) void kUpdM(short* __restrict__ Af,
                                             const short* __restrict__ Avf,
                                             const short* __restrict__ Bf,
                                             const float* __restrict__ lb,
                                             short* __restrict__ hg) {
  __shared__ __align__(16) short Bst[8][2][4][512];   // [wave][buf][ct*2+plane][512] = 64KB
  __shared__ float ssq[8][TRU];
  float (*Ct)[260] = (float(*)[260]) & Bst[0][0][0][0];   // epilogue overlay (49.9KB)
  const int t = threadIdx.x;
  const int rb = blockIdx.x * TRU;
  const int wid = t >> 6;          // 0..7
  const int lane = t & 63;
  const int wc = wid * 32;         // wave col offset (8 waves cover 256 cols)
  const int m16 = lane & 15;
  const int kg = lane >> 4;        // 0..3
  const int r16b = blockIdx.x * 3; // first 16-row group

  floatx4 acc[3][2];
  #pragma unroll
  for (int ct = 0; ct < 2; ct++) {
    float b = lb[wc + ct * 16 + m16];
    #pragma unroll
    for (int rt = 0; rt < 3; rt++) acc[rt][ct] = (floatx4){b, b, b, b};
  }

  short8 aH[2][3], aL[2][3];       // [kc&1][rt] -- static indices after full unroll

  // prologue: stage kc=0, load A(0)
  #pragma unroll
  for (int f = 0; f < 4; f++) {
    const short* g = Bf + ((size_t)((0 * 16 + wid * 2) * 2 + f)) * 512 + lane * 8;
    __builtin_amdgcn_global_load_lds((const __attribute__((address_space(1))) unsigned int*)g,
                                     (__attribute__((address_space(3))) unsigned int*)&Bst[wid][0][f][0],
                                     16, 0, 0);
  }
  #pragma unroll
  for (int rt = 0; rt < 3; rt++) {
    const short* ap = Af + ((size_t)((r16b + rt) * 8 + 0) * 2) * 512 + lane * 8;
    aH[0][rt] = *(const short8*)ap;
    aL[0][rt] = *(const short8*)(ap + 512);
  }

  #pragma unroll
  for (int kc = 0; kc < 16; kc++) {
    const int buf = kc & 1;
    if (kc < 15) {
      #pragma unroll
      for (int f = 0; f < 4; f++) {
        const short* g = Bf + ((size_t)(((kc + 1) * 16 + wid * 2) * 2 + f)) * 512 + lane * 8;
        __builtin_amdgcn_global_load_lds((const __attribute__((address_space(1))) unsigned int*)g,
                                         (__attribute__((address_space(3))) unsigned int*)&Bst[wid][buf ^ 1][f][0],
                                         16, 0, 0);
      }
      asm volatile("s_waitcnt vmcnt(4)" ::: "memory");
    } else {
      asm volatile("s_waitcnt vmcnt(0)" ::: "memory");
    }
    __builtin_amdgcn_sched_barrier(0);
    if (kc < 15) {
      const short* Ab = ((kc + 1) < 8) ? Af : Avf;
      const int kcl = (kc + 1) & 7;
      #pragma unroll
      for (int rt = 0; rt < 3; rt++) {
        const short* ap = Ab + ((size_t)((r16b + rt) * 8 + kcl) * 2) * 512 + lane * 8;
        aH[(kc + 1) & 1][rt] = *(const short8*)ap;
        aL[(kc + 1) & 1][rt] = *(const short8*)(ap + 512);
      }
    }
    #pragma unroll
    for (int ct = 0; ct < 2; ct++) {
      short8 bh = *(const short8*)&Bst[wid][buf][ct * 2 + 0][lane * 8];
      short8 bl = *(const short8*)&Bst[wid][buf][ct * 2 + 1][lane * 8];
      #pragma unroll
      for (int rt = 0; rt < 3; rt++) {
        acc[rt][ct] = __builtin_amdgcn_mfma_f32_16x16x32_bf16(aH[buf][rt], bh, acc[rt][ct], 0, 0, 0);
        acc[rt][ct] = __builtin_amdgcn_mfma_f32_16x16x32_bf16(aH[buf][rt], bl, acc[rt][ct], 0, 0, 0);
        acc[rt][ct] = __builtin_amdgcn_mfma_f32_16x16x32_bf16(aL[buf][rt], bh, acc[rt][ct], 0, 0, 0);
      }
    }
  }

  // ---- epilogue: relu + row l2norm (C/D: col=lane&15, row=(lane>>4)*4+reg)
  float p[3][4];
  #pragma unroll
  for (int rt = 0; rt < 3; rt++)
    #pragma unroll
    for (int reg = 0; reg < 4; reg++) {
      float s = 0.f;
      #pragma unroll
      for (int ct = 0; ct < 2; ct++) {
        float x = fmaxf(acc[rt][ct][reg], 0.f);
        s = fmaf(x, x, s);
      }
      p[rt][reg] = s;
    }
  #pragma unroll
  for (int o = 1; o < 16; o <<= 1)
    #pragma unroll
    for (int rt = 0; rt < 3; rt++)
      #pragma unroll
      for (int reg = 0; reg < 4; reg++)
        p[rt][reg] += __shfl_xor(p[rt][reg], o, 64);
  if (m16 == 0) {
    #pragma unroll
    for (int rt = 0; rt < 3; rt++)
      #pragma unroll
      for (int reg = 0; reg < 4; reg++)
        ssq[wid][rt * 16 + kg * 4 + reg] = p[rt][reg];
  }
  __syncthreads();   // after this barrier all waves are past their last Bst read
  #pragma unroll
  for (int rt = 0; rt < 3; rt++) {
    #pragma unroll
    for (int reg = 0; reg < 4; reg++) {
      int row = rt * 16 + kg * 4 + reg;
      float ss = 0.f;
      #pragma unroll
      for (int ww = 0; ww < 8; ww++) ss += ssq[ww][row];
      float inv = 1.f / fmaxf(sqrtf(ss), 1e-12f);
      #pragma unroll
      for (int ct = 0; ct < 2; ct++) {
        int col = wc + ct * 16 + m16;
        Ct[row][col] = fmaxf(acc[rt][ct][reg], 0.f) * inv;
      }
    }
  }
  __syncthreads();
  // ---- fragment-order split write-back (in-place Af) + bf16 hg, 16B stores
  const int fl = lane;                 // lane-in-fragment
  const int fk = wid;                  // kc 0..7
  #pragma unroll
  for (int r16o = 0; r16o < 3; ++r16o) {
    int row = r16o * 16 + (fl & 15);
    int k0 = fk * 32 + (fl >> 4) * 8;
    float4 xa = *(const float4*)&Ct[row][k0];
    float4 xb = *(const float4*)&Ct[row][k0 + 4];
    short8 H, L;
    H[0] = f2bf(xa.x); H[1] = f2bf(xa.y); H[2] = f2bf(xa.z); H[3] = f2bf(xa.w);
    H[4] = f2bf(xb.x); H[5] = f2bf(xb.y); H[6] = f2bf(xb.z); H[7] = f2bf(xb.w);
    L[0] = f2bf(xa.x - bf2f(H[0])); L[1] = f2bf(xa.y - bf2f(H[1]));
    L[2] = f2bf(xa.z - bf2f(H[2])); L[3] = f2bf(xa.w - bf2f(H[3]));
    L[4] = f2bf(xb.x - bf2f(H[4])); L[5] = f2bf(xb.y - bf2f(H[5]));
    L[6] = f2bf(xb.z - bf2f(H[6])); L[7] = f2bf(xb.w - bf2f(H[7]));
    size_t u = ((size_t)((r16b + r16o) * 8 + fk) * 2) * 512 + (size_t)fl * 8;
    *(short8*)(Af + u) = H;
    *(short8*)(Af + u + 512) = L;
    *(short8*)(hg + (size_t)(rb + row) * DD + k0) = H;
  }
}

// ---------------------------------------------------------------- decode (reads bf16 hg)
__global__ __launch_bounds__(256) void kDec(const short* __restrict__ hg,
                                            const int* __restrict__ aidx,
                                            const float* __restrict__ W4,
                                            const float* __restrict__ W5,
                                            float* __restrict__ Q) {
  __shared__ float tmp[4];
  int b = blockIdx.x, j = threadIdx.x;
  float s = blockSum256(bf2f(hg[(size_t)(NN + b) * DD + j]) * W4[j], tmp);
  int a = aidx[b];
  float za = bf2f(hg[(size_t)a * DD + j]);
  float q = blockSum256(fmaxf(za * s, 0.f) * W5[j], tmp);
  if (j == 0) Q[b] = q;
}

// ---------------------------------------------------------------- launcher
extern "C" void kernel_launch(void* const* d_in, const int* in_sizes, int n_in,
                              void* d_out, int out_size, void* d_ws, size_t ws_size,
                              hipStream_t stream) {
  (void)in_sizes; (void)n_in; (void)out_size; (void)ws_size;
  const int*   edge_src = (const int*)d_in[0];
  const int*   edge_dst = (const int*)d_in[1];
  const float* edge_w   = (const float*)d_in[2];
  const int*   bassign  = (const int*)d_in[3];
  const int*   aidx     = (const int*)d_in[4];
  const float* Xf       = (const float*)d_in[5];
  const float* Xs       = (const float*)d_in[6];
  const float* W1       = (const float*)d_in[7];
  const float* W2       = (const float*)d_in[8];
  const float* W3       = (const float*)d_in[9];
  const float* linW     = (const float*)d_in[10];
  const float* linB     = (const float*)d_in[11];
  const float* W4       = (const float*)d_in[12];
  const float* W5       = (const float*)d_in[13];
  float* Q = (float*)d_out;

  char* base = (char*)d_ws;
  const size_t NB = (size_t)NT * DD * 4;   // 20.5 MB (split-fragment plane-pair bytes)
  short* hg   = (short*)(base);            // NB/2: bf16 h, in-place across depths
  short* Af   = (short*)(base + NB / 2);   // NB: split A-fragments, in-place
  short* Avf  = (short*)(base + NB / 2 + NB);  // NB: split hnv-fragments
  size_t o = NB / 2 + 2 * NB;
  short* Bf   = (short*)(base + o); o += (size_t)DD * 512 * 2 * 2;  // 512 KB, fragment order
  long long* sedge = (long long*)(base + o); o += (size_t)EE * 8;
  int*   snode= (int*)(base + o);   o += (size_t)NN * 4;
  int*   rank = (int*)(base + o);   o += (size_t)EE * 4;
  int*   rankB= (int*)(base + o);   o += (size_t)NN * 4;
  int*   offn = (int*)(base + o);   o += (size_t)(NN + 4) * 4;
  int*   offb = (int*)(base + o);   o += (size_t)(BB + 4) * 4;
  int*   curn = (int*)(base + o);   o += (size_t)NN * 4;
  int*   curb = (int*)(base + o);   o += (size_t)BB * 4;   // contiguous with curn

  hipMemsetAsync(curn, 0, (size_t)(NN + BB) * 4, stream);

  kPre<<<NCB + 64 + NT / 16, 256, 0, stream>>>(Xf, Xs, W1, hg, Af,
                                               edge_dst, bassign, curn, curb,
                                               rank, rankB,
                                               W2, W3, linW, Bf);
  kScan<<<1, 1024, 0, stream>>>(curn, offn, curb, offb);
  kPlace<<<(EE + 255) / 256, 256, 0, stream>>>(edge_src, edge_dst, edge_w, bassign,
                                               offn, offb, rank, rankB, sedge, snode);
  for (int d = 0; d < DEPTH; d++) {
    kAgg<<<4 * (NT / 8), 512, 0, stream>>>(hg, offn, sedge, offb, snode, Avf);
    kUpdM<<<NT / TRU, 512, 0, stream>>>(Af, Avf, Bf, linB, hg);
  }
  kDec<<<BB, 256, 0, stream>>>(hg, aidx, W4, W5, Q);
}